// Round 8
// baseline (607.067 us; speedup 1.0000x reference)
//
#include <hip/hip_runtime.h>
#include <hip/hip_bf16.h>

typedef unsigned short u16;
typedef __bf16 bf16x8 __attribute__((ext_vector_type(8)));
typedef float f32x4 __attribute__((ext_vector_type(4)));

#define S_DIM 2048
#define B_DIM 32
#define H_DIM 1024
#define M_DIM (S_DIM * B_DIM)
#define CROWS 1024      // enc rows per block
#define NSLICE 16       // N = 1024 in 16 slices of 64 cols

__device__ __forceinline__ float fast_tanh(float x) {
  // tanh(x) = 1 - 2/(e^{2x}+1); e->inf => 1, e->0 => -1; no NaN
  float e = __expf(2.0f * x);
  return 1.0f - 2.0f * __builtin_amdgcn_rcpf(e + 1.0f);
}

__device__ __forceinline__ void gload_lds16(const void* g, void* l) {
  __builtin_amdgcn_global_load_lds(
      (const __attribute__((address_space(1))) unsigned int*)g,
      (__attribute__((address_space(3))) unsigned int*)l,
      16, 0, 0);
}

// Convert W_attn[:, H:2H] (f32, row stride 2H) -> W2 bf16 [H][H] row-major
__global__ void wconv_kernel(const float* __restrict__ W, u16* __restrict__ W2) {
  const int h = blockIdx.x;
  const int t = threadIdx.x;
  float4 w4 = *(const float4*)(W + (size_t)h * (2 * H_DIM) + H_DIM + t * 4);
  union { u16 s[4]; uint2 v; } pk;
  pk.s[0] = __builtin_bit_cast(u16, (__bf16)w4.x);
  pk.s[1] = __builtin_bit_cast(u16, (__bf16)w4.y);
  pk.s[2] = __builtin_bit_cast(u16, (__bf16)w4.z);
  pk.s[3] = __builtin_bit_cast(u16, (__bf16)w4.w);
  *(uint2*)(W2 + (size_t)h * H_DIM + t * 4) = pk.v;
}

// u_t[h][b] = dot(hidden[b,:], W_attn[h, 0:H]) + b_attn[h]   (fp32, transposed)
__global__ void uprep_kernel(const float* __restrict__ hidden, const float* __restrict__ W,
                             const float* __restrict__ bias, float* __restrict__ u_t) {
  int t = blockIdx.x * 256 + threadIdx.x;   // 0..131071
  int h = t >> 7;
  int b = (t >> 2) & 31;
  int kq = t & 3;
  const float4* hv = (const float4*)(hidden + (size_t)b * H_DIM) + kq * 64;
  const float4* wv = (const float4*)(W + (size_t)h * (2 * H_DIM)) + kq * 64;
  float acc = 0.f;
  #pragma unroll 4
  for (int i = 0; i < 64; ++i) {
    float4 a = hv[i], w = wv[i];
    acc += a.x * w.x + a.y * w.y + a.z * w.z + a.w * w.w;
  }
  acc += __shfl_xor(acc, 1);
  acc += __shfl_xor(acc, 2);
  if (kq == 0) u_t[(size_t)h * B_DIM + b] = acc + bias[h];
}

// Fused GEMM + tanh + v-dot, B-RESIDENT design:
// Block = 1024 enc rows x 64 W2 cols, FULL K. B slice (64x1024 bf16 = 128 KB)
// staged to LDS ONCE (k-chunk-major slot = (ks*4+q)*64+col, conflict-free,
// linear global_load_lds dest). ONE barrier; then a barrier-free K-loop:
// A streams enc->regs (f32->bf16) in a 4-step pipeline, MFMA accumulates
// acc[8][4] (8 m-groups x 4 col-groups). 512 thr / 8 waves; wave owns rows
// mg*128 + w*16 + [0,16). XCD swizzle: 16 col-slices of one m-chunk share an
// XCD so the 4 MB A-chunk is HBM-fetched once and L2-served to siblings.
__global__ __launch_bounds__(512, 2)
void gemm_kernel(const float* __restrict__ enc, const u16* __restrict__ W2,
                 const float* __restrict__ u_t, const float* __restrict__ v,
                 float* __restrict__ partial) {
  __shared__ u16 B_s[65536];   // 128 KB

  const int tid  = threadIdx.x;
  const int lane = tid & 63;
  const int w    = tid >> 6;    // 0..7
  const int q    = lane >> 4;   // 0..3
  const int c16  = lane & 15;

  // XCD-aware decode (bijective over 1024 blocks, xcd = blockIdx%8 = mc%8):
  const int bidx = blockIdx.x;
  const int t7   = bidx >> 3;
  const int ns   = t7 & 15;                  // n-slice 0..15
  const int mc   = (bidx & 7) + 8 * (t7 >> 4); // m-chunk 0..63
  const int m0   = mc * CROWS;
  const int n0   = ns * 64;

  // ---- stage B slice once: 8192 slots of 16B; slot=(kq)*64+col ----
  #pragma unroll
  for (int j = 0; j < 16; ++j) {
    const int slot = j * 512 + tid;
    gload_lds16(W2 + (size_t)(n0 + (slot & 63)) * H_DIM + (slot >> 6) * 8,
                &B_s[slot * 8]);
  }

  // A row base pointers (per-lane): row = m0 + mg*128 + w*16 + c16, k base q*8
  const float* pA[8];
  #pragma unroll
  for (int mg = 0; mg < 8; ++mg)
    pA[mg] = enc + (size_t)(m0 + mg * 128 + w * 16 + c16) * H_DIM + q * 8;

  f32x4 acc[8][4];
  #pragma unroll
  for (int mg = 0; mg < 8; ++mg)
    #pragma unroll
    for (int g = 0; g < 4; ++g) {
      f32x4 z = {0.f, 0.f, 0.f, 0.f};
      acc[mg][g] = z;
    }

  __syncthreads();   // B_s resident from here on; the ONLY barrier

  // B-frag read: u16 index = ks*2048 + q*512 + g*128 + c16*8
  #define BREAD(g, ks) (*(const bf16x8*)&B_s[(ks) * 2048 + q * 512 + (g) * 128 + c16 * 8])

  #define CVT8(dst, fa, fb)                                                   \
    {                                                                         \
      union { u16 s[8]; bf16x8 v8; } pk;                                      \
      pk.s[0] = __builtin_bit_cast(u16, (__bf16)(fa).x);                      \
      pk.s[1] = __builtin_bit_cast(u16, (__bf16)(fa).y);                      \
      pk.s[2] = __builtin_bit_cast(u16, (__bf16)(fa).z);                      \
      pk.s[3] = __builtin_bit_cast(u16, (__bf16)(fa).w);                      \
      pk.s[4] = __builtin_bit_cast(u16, (__bf16)(fb).x);                      \
      pk.s[5] = __builtin_bit_cast(u16, (__bf16)(fb).y);                      \
      pk.s[6] = __builtin_bit_cast(u16, (__bf16)(fb).z);                      \
      pk.s[7] = __builtin_bit_cast(u16, (__bf16)(fb).w);                      \
      dst = pk.v8;                                                            \
    }

  // prime: B frags for ks=0, A pairs for (ks=0, mg=0..3)
  bf16x8 bc0 = BREAD(0, 0), bc1 = BREAD(1, 0), bc2 = BREAD(2, 0), bc3 = BREAD(3, 0);
  f32x4 p0a = *(const f32x4*)(pA[0]), p0b = *(const f32x4*)(pA[0] + 4);
  f32x4 p1a = *(const f32x4*)(pA[1]), p1b = *(const f32x4*)(pA[1] + 4);
  f32x4 p2a = *(const f32x4*)(pA[2]), p2b = *(const f32x4*)(pA[2] + 4);
  f32x4 p3a = *(const f32x4*)(pA[3]), p3b = *(const f32x4*)(pA[3] + 4);

  // MG step: consume pair PJ (cvt+4 MFMA into acc[MG]), refill PJ from pA[RM]+off
  #define MGSTEP(MG, PJa, PJb, RM, OFF)                                       \
    {                                                                         \
      bf16x8 af;                                                              \
      CVT8(af, PJa, PJb);                                                     \
      PJa = *(const f32x4*)(pA[RM] + (OFF));                                  \
      PJb = *(const f32x4*)(pA[RM] + (OFF) + 4);                              \
      acc[MG][0] = __builtin_amdgcn_mfma_f32_16x16x32_bf16(af, bc0, acc[MG][0], 0, 0, 0); \
      acc[MG][1] = __builtin_amdgcn_mfma_f32_16x16x32_bf16(af, bc1, acc[MG][1], 0, 0, 0); \
      acc[MG][2] = __builtin_amdgcn_mfma_f32_16x16x32_bf16(af, bc2, acc[MG][2], 0, 0, 0); \
      acc[MG][3] = __builtin_amdgcn_mfma_f32_16x16x32_bf16(af, bc3, acc[MG][3], 0, 0, 0); \
    }

  for (int ks = 0; ks < 32; ++ks) {
    const int kn = (ks < 31) ? ks + 1 : 31;
    const int o0 = ks * 32;        // refill offset for mg 4..7 of this ks
    const int o1 = kn * 32;        // refill offset for mg 0..3 of next ks
    bf16x8 bn0 = BREAD(0, kn), bn1 = BREAD(1, kn), bn2 = BREAD(2, kn), bn3 = BREAD(3, kn);
    MGSTEP(0, p0a, p0b, 4, o0)
    MGSTEP(1, p1a, p1b, 5, o0)
    MGSTEP(2, p2a, p2b, 6, o0)
    MGSTEP(3, p3a, p3b, 7, o0)
    MGSTEP(4, p0a, p0b, 0, o1)
    MGSTEP(5, p1a, p1b, 1, o1)
    MGSTEP(6, p2a, p2b, 2, o1)
    MGSTEP(7, p3a, p3b, 3, o1)
    bc0 = bn0; bc1 = bn1; bc2 = bn2; bc3 = bn3;
  }

  // ---- epilogue: rowsum_h v[h]*tanh(acc + u[b][h]) over this block's 64 cols ----
  const int ub = (w & 1) * 16 + q * 4;   // b base for this thread's acc rows
  float vg[4];
  f32x4 ug[4];
  #pragma unroll
  for (int g = 0; g < 4; ++g) {
    const int h = n0 + g * 16 + c16;
    vg[g] = v[h];
    ug[g] = *(const f32x4*)(u_t + (size_t)h * B_DIM + ub);
  }

  f32x4 rs[8];
  #pragma unroll
  for (int mg = 0; mg < 8; ++mg) {
    f32x4 z = {0.f, 0.f, 0.f, 0.f};
    rs[mg] = z;
    #pragma unroll
    for (int g = 0; g < 4; ++g)
      #pragma unroll
      for (int r = 0; r < 4; ++r)
        rs[mg][r] += vg[g] * fast_tanh(acc[mg][g][r] + ug[g][r]);
  }

  // reduce over the 16 col-lanes; c16==0 lanes hold final partial row sums
  #pragma unroll
  for (int mg = 0; mg < 8; ++mg) {
    #pragma unroll
    for (int r = 0; r < 4; ++r) {
      float s = rs[mg][r];
      s += __shfl_xor(s, 1);
      s += __shfl_xor(s, 2);
      s += __shfl_xor(s, 4);
      s += __shfl_xor(s, 8);
      rs[mg][r] = s;
    }
  }
  if (c16 == 0) {
    #pragma unroll
    for (int mg = 0; mg < 8; ++mg) {
      const int rowb = mg * 128 + w * 16 + q * 4;       // row base within chunk
      const int sidx = (m0 + rowb) >> 5;                // same for r=0..3
      #pragma unroll
      for (int r = 0; r < 4; ++r)
        partial[(size_t)ns * M_DIM + (size_t)(ub + r) * S_DIM + sidx] = rs[mg][r];
    }
  }
  #undef BREAD
  #undef CVT8
  #undef MGSTEP
}

// softmax over S per batch row b, fused with the 16-slice partial reduction.
// partial layout: [ns][b][s]; out[b][0][s].
__global__ void softmax_kernel(const float* __restrict__ partial, float* __restrict__ out) {
  const int b = blockIdx.x;
  const int t = threadIdx.x;        // 256
  const int lane = t & 63, wid = t >> 6;
  __shared__ float redm[4], reds[4];
  float loc[8];
  float mx = -3.0e38f;
  #pragma unroll
  for (int i = 0; i < 8; ++i) {
    const int s = i * 256 + t;
    float a = 0.f;
    #pragma unroll
    for (int j = 0; j < NSLICE; ++j)
      a += partial[(size_t)j * M_DIM + (size_t)b * S_DIM + s];
    loc[i] = a;
    mx = fmaxf(mx, a);
  }
  #pragma unroll
  for (int off = 1; off < 64; off <<= 1) mx = fmaxf(mx, __shfl_xor(mx, off));
  if (lane == 0) redm[wid] = mx;
  __syncthreads();
  mx = fmaxf(fmaxf(redm[0], redm[1]), fmaxf(redm[2], redm[3]));
  float sum = 0.f;
  #pragma unroll
  for (int i = 0; i < 8; ++i) { loc[i] = __expf(loc[i] - mx); sum += loc[i]; }
  #pragma unroll
  for (int off = 1; off < 64; off <<= 1) sum += __shfl_xor(sum, off);
  if (lane == 0) reds[wid] = sum;
  __syncthreads();
  sum = reds[0] + reds[1] + reds[2] + reds[3];
  float inv = 1.0f / sum;
  #pragma unroll
  for (int i = 0; i < 8; ++i) out[(size_t)b * S_DIM + i * 256 + t] = loc[i] * inv;
}

extern "C" void kernel_launch(void* const* d_in, const int* in_sizes, int n_in,
                              void* d_out, int out_size, void* d_ws, size_t ws_size,
                              hipStream_t stream) {
  const float* hidden = (const float*)d_in[0];
  const float* enc    = (const float*)d_in[1];
  const float* W      = (const float*)d_in[2];
  const float* bias   = (const float*)d_in[3];
  const float* v      = (const float*)d_in[4];
  float* out = (float*)d_out;

  char* ws = (char*)d_ws;
  u16*   W2      = (u16*)ws;                                   // 2 MB
  float* u_t     = (float*)(ws + (2u << 20));                  // 128 KB [H][B]
  float* partial = (float*)(ws + (2u << 20) + (256u << 10));   // 4 MB [16][B][S]

  wconv_kernel<<<H_DIM, 256, 0, stream>>>(W, W2);
  uprep_kernel<<<512, 256, 0, stream>>>(hidden, W, bias, u_t);
  gemm_kernel<<<(M_DIM / CROWS) * NSLICE, 512, 0, stream>>>(enc, W2, u_t, v, partial);
  softmax_kernel<<<B_DIM, 256, 0, stream>>>(partial, out);
}

// Round 9
// 437.740 us; speedup vs baseline: 1.3868x; 1.3868x over previous
//
#include <hip/hip_runtime.h>
#include <hip/hip_bf16.h>

typedef unsigned short u16;
typedef __bf16 bf16x8 __attribute__((ext_vector_type(8)));
typedef float f32x4 __attribute__((ext_vector_type(4)));

#define S_DIM 2048
#define B_DIM 32
#define H_DIM 1024
#define M_DIM (S_DIM * B_DIM)
#define NSLICE 4        // N = 1024 in 4 slices of 256 cols
#define NT 16           // K = 1024 in 16 tiles of 64

__device__ __forceinline__ float fast_tanh(float x) {
  // tanh(x) = 1 - 2/(e^{2x}+1); e->inf => 1, e->0 => -1; no NaN
  float e = __expf(2.0f * x);
  return 1.0f - 2.0f * __builtin_amdgcn_rcpf(e + 1.0f);
}

__device__ __forceinline__ void gload_lds16(const void* g, void* l) {
  __builtin_amdgcn_global_load_lds(
      (const __attribute__((address_space(1))) unsigned int*)g,
      (__attribute__((address_space(3))) unsigned int*)l,
      16, 0, 0);
}

__device__ __forceinline__ uint4 pack8(float4 fa, float4 fb) {
  union { u16 s[8]; uint4 v; } pk;
  pk.s[0] = __builtin_bit_cast(u16, (__bf16)fa.x);
  pk.s[1] = __builtin_bit_cast(u16, (__bf16)fa.y);
  pk.s[2] = __builtin_bit_cast(u16, (__bf16)fa.z);
  pk.s[3] = __builtin_bit_cast(u16, (__bf16)fa.w);
  pk.s[4] = __builtin_bit_cast(u16, (__bf16)fb.x);
  pk.s[5] = __builtin_bit_cast(u16, (__bf16)fb.y);
  pk.s[6] = __builtin_bit_cast(u16, (__bf16)fb.z);
  pk.s[7] = __builtin_bit_cast(u16, (__bf16)fb.w);
  return pk.v;
}

// Convert W_attn[:, H:2H] (f32, row stride 2H) -> W2 bf16 [H][H] row-major
__global__ void wconv_kernel(const float* __restrict__ W, u16* __restrict__ W2) {
  const int h = blockIdx.x;
  const int t = threadIdx.x;
  float4 w4 = *(const float4*)(W + (size_t)h * (2 * H_DIM) + H_DIM + t * 4);
  union { u16 s[4]; uint2 v; } pk;
  pk.s[0] = __builtin_bit_cast(u16, (__bf16)w4.x);
  pk.s[1] = __builtin_bit_cast(u16, (__bf16)w4.y);
  pk.s[2] = __builtin_bit_cast(u16, (__bf16)w4.z);
  pk.s[3] = __builtin_bit_cast(u16, (__bf16)w4.w);
  *(uint2*)(W2 + (size_t)h * H_DIM + t * 4) = pk.v;
}

// u_t[h][b] = dot(hidden[b,:], W_attn[h, 0:H]) + b_attn[h]   (fp32, transposed)
__global__ void uprep_kernel(const float* __restrict__ hidden, const float* __restrict__ W,
                             const float* __restrict__ bias, float* __restrict__ u_t) {
  int t = blockIdx.x * 256 + threadIdx.x;   // 0..131071
  int h = t >> 7;
  int b = (t >> 2) & 31;
  int kq = t & 3;
  const float4* hv = (const float4*)(hidden + (size_t)b * H_DIM) + kq * 64;
  const float4* wv = (const float4*)(W + (size_t)h * (2 * H_DIM)) + kq * 64;
  float acc = 0.f;
  #pragma unroll 4
  for (int i = 0; i < 64; ++i) {
    float4 a = hv[i], w = wv[i];
    acc += a.x * w.x + a.y * w.y + a.z * w.z + a.w * w.w;
  }
  acc += __shfl_xor(acc, 1);
  acc += __shfl_xor(acc, 2);
  if (kq == 0) u_t[(size_t)h * B_DIM + b] = acc + bias[h];
}

// Fused GEMM + tanh + v-dot, 256x256 tile, BK=64, phase-split schedule.
// 512 thr / 8 waves (2m x 4n), wave tile 128x64, acc[8][4] f32x4.
// Per K-tile: 4 phases x 16 MFMA, raw s_barrier between phases (no drain);
// vmcnt(0)+lgkmcnt(0) only at the tile boundary. Staging for t+1 split across
// phases (T14): A f32 loads p0/p1, B global_load_lds p1, A cvt+ds_write p2/p3.
// LDS kq-major [kq][row]x8elems: linear gload dest, 16-lane-contiguous
// ds ops (R4/R7-measured 0 conflicts). XCD swizzle: 4 n-siblings of each
// A-panel share an XCD. Partial scores per n-slice; softmax sums 4 slices.
__global__ __launch_bounds__(512, 2)
void gemm_kernel(const float* __restrict__ enc, const u16* __restrict__ W2,
                 const float* __restrict__ u_t, const float* __restrict__ v,
                 float* __restrict__ partial) {
  __shared__ u16 A_s[32768];      // 2 bufs x 16384 u16 (256 rows x 64 k)
  __shared__ u16 B_s[32768];
  __shared__ float red_s[1024];   // [wn][256 rows]

  const int tid  = threadIdx.x;
  const int lane = tid & 63;
  const int w    = tid >> 6;    // 0..7
  const int wm   = w >> 2;      // 0..1
  const int wn   = w & 3;       // 0..3
  const int q    = lane >> 4;   // 0..3
  const int c16  = lane & 15;

  // XCD-bijective decode (1024 blocks): ns = (b>>3)&3, mt = (b&7) + 8*(b>>5).
  // All 4 n-siblings of an m-tile share b&7 -> same XCD (xcd = blockIdx%8).
  const int bidx = blockIdx.x;
  const int ns   = (bidx >> 3) & 3;
  const int mt   = (bidx & 7) + 8 * (bidx >> 5);
  const int m0   = mt * 256;
  const int n0   = ns * 256;

  // staging coords: thread covers row_s for kq pages {kqh, 2+kqh, 4+kqh, 6+kqh}
  const int row_s = tid & 255;
  const int kqh   = tid >> 8;    // 0..1
  const float* apbase = enc + (size_t)(m0 + row_s) * H_DIM + kqh * 8;
  const u16*   bpbase = W2 + (size_t)(n0 + row_s) * H_DIM + kqh * 8;

  f32x4 acc[8][4];
  #pragma unroll
  for (int mf = 0; mf < 8; ++mf)
    #pragma unroll
    for (int nf = 0; nf < 4; ++nf) {
      f32x4 z = {0.f, 0.f, 0.f, 0.f};
      acc[mf][nf] = z;
    }

  // ---- prologue: stage tile 0 into buf0 ----
  #pragma unroll
  for (int j = 0; j < 4; ++j)
    gload_lds16(bpbase + 16 * j, &B_s[(j * 512 + tid) * 8]);
  #pragma unroll
  for (int j = 0; j < 4; ++j) {
    float4 fa = *(const float4*)(apbase + 16 * j);
    float4 fb = *(const float4*)(apbase + 16 * j + 4);
    *(uint4*)&A_s[(j * 512 + tid) * 8] = pack8(fa, fb);
  }
  __syncthreads();

  const int aro = wm * 128 + c16;   // + mh*64 + mf*16
  const int bco = wn * 64 + c16;    // + nf*16

  #define RD_A(dst, KK, MH)                                                   \
    { _Pragma("unroll")                                                       \
      for (int mf = 0; mf < 4; ++mf)                                          \
        dst[mf] = *(const bf16x8*)&A_s[cb + ((((KK)*4 + q) * 256) + aro +     \
                                             (MH)*64 + mf*16) * 8]; }
  #define RD_B(dst, KK)                                                       \
    { _Pragma("unroll")                                                       \
      for (int nf = 0; nf < 4; ++nf)                                          \
        dst[nf] = *(const bf16x8*)&B_s[cb + ((((KK)*4 + q) * 256) + bco +     \
                                             nf*16) * 8]; }
  #define MF16(MB, AA, BB)                                                    \
    { __builtin_amdgcn_s_setprio(1);                                          \
      _Pragma("unroll")                                                       \
      for (int mf = 0; mf < 4; ++mf)                                          \
        _Pragma("unroll")                                                     \
        for (int nf = 0; nf < 4; ++nf)                                        \
          acc[(MB)+mf][nf] = __builtin_amdgcn_mfma_f32_16x16x32_bf16(         \
              AA[mf], BB[nf], acc[(MB)+mf][nf], 0, 0, 0);                     \
      __builtin_amdgcn_s_setprio(0); }
  #define PBAR() { __builtin_amdgcn_s_barrier(); __builtin_amdgcn_sched_barrier(0); }

  #pragma unroll 2
  for (int t = 0; t < NT; ++t) {
    const int cb   = (t & 1) << 14;   // current buf base (u16 idx)
    const int nbuf = cb ^ 16384;      // next buf
    const bool pf  = (t + 1 < NT);
    const int tko  = (t + 1) * 64;
    float4 af0[4], af1[4];
    bf16x8 a0[4], a1[4], b0[4], b1[4];

    // ---- phase 0: (mh0, kk0); issue A loads slots 0,1 for t+1 ----
    if (pf) {
      af0[0] = *(const float4*)(apbase + tko);
      af0[1] = *(const float4*)(apbase + tko + 4);
      af0[2] = *(const float4*)(apbase + tko + 16);
      af0[3] = *(const float4*)(apbase + tko + 20);
    }
    RD_A(a0, 0, 0); RD_B(b0, 0);
    MF16(0, a0, b0);
    PBAR();

    // ---- phase 1: (mh1, kk0); issue A slots 2,3 + all B gloads for t+1 ----
    if (pf) {
      af1[0] = *(const float4*)(apbase + tko + 32);
      af1[1] = *(const float4*)(apbase + tko + 36);
      af1[2] = *(const float4*)(apbase + tko + 48);
      af1[3] = *(const float4*)(apbase + tko + 52);
      #pragma unroll
      for (int j = 0; j < 4; ++j)
        gload_lds16(bpbase + tko + 16 * j, &B_s[nbuf + (j * 512 + tid) * 8]);
    }
    RD_A(a1, 0, 1);
    MF16(4, a1, b0);
    PBAR();

    // ---- phase 2: (mh0, kk1); cvt+write A slots 0,1 ----
    if (pf) {
      *(uint4*)&A_s[nbuf + tid * 8]         = pack8(af0[0], af0[1]);
      *(uint4*)&A_s[nbuf + (512 + tid) * 8] = pack8(af0[2], af0[3]);
    }
    RD_A(a0, 1, 0); RD_B(b1, 1);
    MF16(0, a0, b1);
    PBAR();

    // ---- phase 3: (mh1, kk1); cvt+write A slots 2,3; tile-boundary drain ----
    if (pf) {
      *(uint4*)&A_s[nbuf + (1024 + tid) * 8] = pack8(af1[0], af1[1]);
      *(uint4*)&A_s[nbuf + (1536 + tid) * 8] = pack8(af1[2], af1[3]);
    }
    RD_A(a1, 1, 1);
    MF16(4, a1, b1);
    asm volatile("s_waitcnt vmcnt(0) lgkmcnt(0)" ::: "memory");
    __builtin_amdgcn_s_barrier();
    __builtin_amdgcn_sched_barrier(0);
  }
  #undef RD_A
  #undef RD_B
  #undef MF16
  #undef PBAR

  // ---- epilogue: rowsum_h v[h]*tanh(acc + u[b][h]) over this slice's 256 cols ----
  f32x4 rs[8];
  #pragma unroll
  for (int mf = 0; mf < 8; ++mf) { f32x4 z = {0.f, 0.f, 0.f, 0.f}; rs[mf] = z; }

  #pragma unroll
  for (int nf = 0; nf < 4; ++nf) {
    const int h = n0 + wn * 64 + nf * 16 + c16;
    const float vh = v[h];
    const f32x4 ue = *(const f32x4*)(u_t + (size_t)h * B_DIM + q * 4);
    const f32x4 uo = *(const f32x4*)(u_t + (size_t)h * B_DIM + 16 + q * 4);
    #pragma unroll
    for (int mf = 0; mf < 8; ++mf)
      #pragma unroll
      for (int j = 0; j < 4; ++j) {
        const float uu = (mf & 1) ? uo[j] : ue[j];
        rs[mf][j] += vh * fast_tanh(acc[mf][nf][j] + uu);
      }
  }
  // reduce over 16 col-lanes, then across the 4 n-waves via LDS
  #pragma unroll
  for (int mf = 0; mf < 8; ++mf)
    #pragma unroll
    for (int j = 0; j < 4; ++j) {
      float s = rs[mf][j];
      s += __shfl_xor(s, 1);
      s += __shfl_xor(s, 2);
      s += __shfl_xor(s, 4);
      s += __shfl_xor(s, 8);
      if (c16 == 0) red_s[wn * 256 + wm * 128 + mf * 16 + q * 4 + j] = s;
    }
  __syncthreads();
  if (tid < 256) {
    float s = red_s[tid] + red_s[256 + tid] + red_s[512 + tid] + red_s[768 + tid];
    partial[(size_t)ns * M_DIM + (size_t)(tid & 31) * S_DIM + ((m0 + tid) >> 5)] = s;
  }
}

// softmax over S per batch row b, fused with the 4-slice partial reduction.
// partial layout: [ns][b][s]; out[b][0][s].
__global__ void softmax_kernel(const float* __restrict__ partial, float* __restrict__ out) {
  const int b = blockIdx.x;
  const int t = threadIdx.x;        // 256
  const int lane = t & 63, wid = t >> 6;
  __shared__ float redm[4], reds[4];
  float loc[8];
  float mx = -3.0e38f;
  #pragma unroll
  for (int i = 0; i < 8; ++i) {
    const int s = i * 256 + t;
    float a = 0.f;
    #pragma unroll
    for (int j = 0; j < NSLICE; ++j)
      a += partial[(size_t)j * M_DIM + (size_t)b * S_DIM + s];
    loc[i] = a;
    mx = fmaxf(mx, a);
  }
  #pragma unroll
  for (int off = 1; off < 64; off <<= 1) mx = fmaxf(mx, __shfl_xor(mx, off));
  if (lane == 0) redm[wid] = mx;
  __syncthreads();
  mx = fmaxf(fmaxf(redm[0], redm[1]), fmaxf(redm[2], redm[3]));
  float sum = 0.f;
  #pragma unroll
  for (int i = 0; i < 8; ++i) { loc[i] = __expf(loc[i] - mx); sum += loc[i]; }
  #pragma unroll
  for (int off = 1; off < 64; off <<= 1) sum += __shfl_xor(sum, off);
  if (lane == 0) reds[wid] = sum;
  __syncthreads();
  sum = reds[0] + reds[1] + reds[2] + reds[3];
  float inv = 1.0f / sum;
  #pragma unroll
  for (int i = 0; i < 8; ++i) out[(size_t)b * S_DIM + i * 256 + t] = loc[i] * inv;
}

extern "C" void kernel_launch(void* const* d_in, const int* in_sizes, int n_in,
                              void* d_out, int out_size, void* d_ws, size_t ws_size,
                              hipStream_t stream) {
  const float* hidden = (const float*)d_in[0];
  const float* enc    = (const float*)d_in[1];
  const float* W      = (const float*)d_in[2];
  const float* bias   = (const float*)d_in[3];
  const float* v      = (const float*)d_in[4];
  float* out = (float*)d_out;

  char* ws = (char*)d_ws;
  u16*   W2      = (u16*)ws;                                   // 2 MB
  float* u_t     = (float*)(ws + (2u << 20));                  // 128 KB [H][B]
  float* partial = (float*)(ws + (2304u << 10));               // 1 MB [4][B][S]

  wconv_kernel<<<H_DIM, 256, 0, stream>>>(W, W2);
  uprep_kernel<<<512, 256, 0, stream>>>(hidden, W, bias, u_t);
  gemm_kernel<<<(M_DIM / 256) * NSLICE, 512, 0, stream>>>(enc, W2, u_t, v, partial);
  softmax_kernel<<<B_DIM, 256, 0, stream>>>(partial, out);
}